// Round 5
// baseline (162.566 us; speedup 1.0000x reference)
//
#include <hip/hip_runtime.h>

#define H 1024
#define W 1024
#define F 32
#define K 25
#define TW 512            // output px per block (2 strided px per thread)
#define HALO 2
#define LROW (TW + 8)     // 520 floats per LDS row

// Prep: transpose weights skv[f][k] -> wt[k][f] (contiguous f -> s_load_dwordx8)
// and fold (dx,dy) into a single LDS dword offset per k.
__global__ __launch_bounds__(832) void prep(const float* __restrict__ skv,
                                            const int* __restrict__ idx,
                                            float* __restrict__ wt,
                                            int* __restrict__ loff) {
    const int i = threadIdx.x;
    if (i < F * K) {
        const int f = i % F, k = i / F;
        wt[i] = skv[f * K + k];            // wt[k*F + f]
    }
    if (i < K) {
        loff[i] = (idx[2 * i + 1] + HALO) * LROW + (idx[2 * i] + HALO);
    }
}

__global__ __launch_bounds__(256) void sparse_conv(const float* __restrict__ in,
                                                   const float* __restrict__ wt,
                                                   const int* __restrict__ loff,
                                                   float* __restrict__ out) {
    __shared__ float tile[5 * LROW];
    const int t  = threadIdx.x;
    const int x0 = blockIdx.x * TW;
    const int h  = blockIdx.y;

    // Stage rows h-2..h+2, cols x0-2 .. x0+513 (516 floats), zero OOB.
    // Stride-4B writes: conflict-free.
    for (int r = 0; r < 5; ++r) {
        const int gy = h + r - HALO;
        const bool rowok = (gy >= 0 && gy < H);
        #pragma unroll
        for (int j = 0; j < 2; ++j) {
            const int c  = t + j * 256;
            const int gx = x0 + c - HALO;
            float v = 0.f;
            if (rowok && gx >= 0 && gx < W) v = in[(size_t)gy * W + gx];
            tile[r * LROW + c] = v;
        }
        if (t < 4) {
            const int c  = 512 + t;
            const int gx = x0 + c - HALO;
            float v = 0.f;
            if (rowok && gx >= 0 && gx < W) v = in[(size_t)gy * W + gx];
            tile[r * LROW + c] = v;
        }
    }
    __syncthreads();

    const size_t obase = (size_t)h * W + x0 + t;

    for (int fc = 0; fc < F; fc += 8) {          // f-chunks: compute 8, store 8
        float a0[8], a1[8];
        #pragma unroll
        for (int f = 0; f < 8; ++f) { a0[f] = 0.f; a1[f] = 0.f; }

        #pragma unroll
        for (int k = 0; k < K; ++k) {
            const int off = loff[k];                   // uniform -> SGPR
            const float v0 = tile[off + t];            // stride-4B ds_read_b32: conflict-free
            const float v1 = tile[off + t + 256];
            #pragma unroll
            for (int f = 0; f < 8; ++f) {
                const float wv = wt[k * F + fc + f];   // uniform -> s_load_dwordx8
                a0[f] = fmaf(wv, v0, a0[f]);
                a1[f] = fmaf(wv, v1, a1[f]);
            }
        }

        #pragma unroll
        for (int f = 0; f < 8; ++f) {
            float* p = out + (size_t)(fc + f) * (H * W) + obase;
            __builtin_nontemporal_store(a0[f], p);         // 256B/wave contiguous
            __builtin_nontemporal_store(a1[f], p + 256);
        }
    }
}

extern "C" void kernel_launch(void* const* d_in, const int* in_sizes, int n_in,
                              void* d_out, int out_size, void* d_ws, size_t ws_size,
                              hipStream_t stream) {
    const float* in  = (const float*)d_in[0];
    const float* skv = (const float*)d_in[1];
    const int*   idx = (const int*)d_in[2];
    float* out = (float*)d_out;
    float* wt  = (float*)d_ws;                          // 800 floats
    int*   loff = (int*)((char*)d_ws + 4096);           // 25 ints

    prep<<<1, 832, 0, stream>>>(skv, idx, wt, loff);
    sparse_conv<<<dim3(W / TW, H), dim3(256), 0, stream>>>(in, wt, loff, out);
}